// Round 6
// baseline (221.210 us; speedup 1.0000x reference)
//
#include <hip/hip_runtime.h>

#define HW 65536
#define CH 64
#define NPIXF 4194304.0f

typedef __attribute__((ext_vector_type(8))) short short8;
typedef __attribute__((ext_vector_type(4))) short short4v;
typedef __attribute__((ext_vector_type(8))) __bf16 bf16x8;
typedef __attribute__((ext_vector_type(4))) float f32x4;

__device__ __forceinline__ unsigned short f2bf(float f) {
  unsigned int u = __builtin_bit_cast(unsigned int, f);
  u += 0x7FFFu + ((u >> 16) & 1u);
  return (unsigned short)(u >> 16);
}
__device__ __forceinline__ int swz(int p, int cc) { return cc ^ ((p ^ (p >> 3)) & 7); }

// ws float layout: [16..31]=sum_x [32..47]=sumsq_x [48..63]=sum_h [64..79]=sumsq_h
//                  [128..191]=u1  [192..255]=v1    [256..271]=u2  [272..287]=v2
// bytes: a1 bf16[64][64] @2048, a2 bf16[16][64] @10240,
//        xb16 @16384: bf16 [sample][p][64c]  (pixel-major, MFMA-B-fragment order)

// ---- k_pre: weight prep + zero stat accumulators (1 block, 256 thr) ----
__global__ __launch_bounds__(256) void k_pre(
    const float* __restrict__ w1, const float* __restrict__ b1,
    const float* __restrict__ s1, const float* __restrict__ gb1,
    const float* __restrict__ w2, const float* __restrict__ b2,
    const float* __restrict__ s2, const float* __restrict__ gb2,
    float* __restrict__ wsf,
    unsigned short* __restrict__ a1, unsigned short* __restrict__ a2) {
  const int tid = threadIdx.x;
  {
    int o = tid >> 2, q = tid & 3;
    float u = 0.f, v = 0.f;
    unsigned short loc[16];
#pragma unroll
    for (int i = 0; i < 16; ++i) {
      int c = q * 16 + i;
      float w = w1[o * 64 + c];
      float wsc = w * s1[c];
      loc[i] = f2bf(wsc);
      u += wsc;
      v += w * gb1[c];
    }
    *(short8*)(a1 + o * 64 + q * 16) = *(short8*)loc;
    *(short8*)(a1 + o * 64 + q * 16 + 8) = *(short8*)(loc + 8);
    u += __shfl_xor(u, 1, 64); u += __shfl_xor(u, 2, 64);
    v += __shfl_xor(v, 1, 64); v += __shfl_xor(v, 2, 64);
    if (q == 0) { wsf[128 + o] = u; wsf[192 + o] = b1[o] + v; }
  }
  if (tid < 64) {
    int o = tid >> 2, q = tid & 3;
    float u = 0.f, v = 0.f;
    unsigned short loc[16];
#pragma unroll
    for (int i = 0; i < 16; ++i) {
      int c = q * 16 + i;
      float w = (o < 6) ? w2[o * 64 + c] : 0.f;
      float wsc = w * s2[c];
      loc[i] = f2bf(wsc);
      u += wsc;
      v += w * gb2[c];
    }
    *(short8*)(a2 + o * 64 + q * 16) = *(short8*)loc;
    *(short8*)(a2 + o * 64 + q * 16 + 8) = *(short8*)(loc + 8);
    u += __shfl_xor(u, 1, 64); u += __shfl_xor(u, 2, 64);
    v += __shfl_xor(v, 1, 64); v += __shfl_xor(v, 2, 64);
    if (q == 0) { wsf[256 + o] = u; wsf[272 + o] = ((o < 6) ? b2[o] : 0.f) + v; }
  }
  if (tid >= 192) wsf[16 + (tid - 192)] = 0.f;  // zero 64 stat slots
}

// ---- k1: x stats + bf16 convert + in-register transpose -> xb16[p][64c] ----
__global__ __launch_bounds__(256) void k1(const float* __restrict__ x,
                                          float* __restrict__ wsf,
                                          unsigned short* __restrict__ xb16) {
  __shared__ float red[8];
  const int tid = threadIdx.x;
  const int l = tid & 63, w = tid >> 6;
  const int b = blockIdx.y;
  const int p0 = blockIdx.x * 256;          // 256 pixels per block
  const float* xs = x + (size_t)b * CH * HW;
  unsigned short* xo = xb16 + (size_t)b * CH * HW;

  const int c0 = (tid >> 5) * 8;            // 8 channels per thread
  const int px = p0 + (tid & 31) * 8;       // 8 pixels per thread

  f32x4 va[8], vb[8];
  const float* base = xs + (size_t)c0 * HW + px;
#pragma unroll
  for (int i = 0; i < 8; ++i) {
    va[i] = *(const f32x4*)(base + (size_t)i * HW);
    vb[i] = *(const f32x4*)(base + (size_t)i * HW + 4);
  }

  float s = 0.f, q = 0.f;
#pragma unroll
  for (int i = 0; i < 8; ++i)
#pragma unroll
    for (int j = 0; j < 4; ++j) {
      float f0 = va[i][j]; s += f0; q += f0 * f0;
      float f1 = vb[i][j]; s += f1; q += f1 * f1;
    }

  // in-register transpose: write 8 ch of one pixel as one short8
#pragma unroll
  for (int dp = 0; dp < 4; ++dp) {
    short8 w8;
#pragma unroll
    for (int i = 0; i < 8; ++i) w8[i] = (short)f2bf(va[i][dp]);
    *(short8*)(xo + (size_t)(px + dp) * CH + c0) = w8;
  }
#pragma unroll
  for (int dp = 0; dp < 4; ++dp) {
    short8 w8;
#pragma unroll
    for (int i = 0; i < 8; ++i) w8[i] = (short)f2bf(vb[i][dp]);
    *(short8*)(xo + (size_t)(px + 4 + dp) * CH + c0) = w8;
  }

#pragma unroll
  for (int off = 32; off > 0; off >>= 1) {
    s += __shfl_down(s, off, 64);
    q += __shfl_down(q, off, 64);
  }
  if (l == 0) { red[w] = s; red[4 + w] = q; }
  __syncthreads();
  if (tid == 0) {
    atomicAdd(wsf + 16 + b, red[0] + red[1] + red[2] + red[3]);
    atomicAdd(wsf + 32 + b, red[4] + red[5] + red[6] + red[7]);
  }
}

// ---- k2: conv1 (B-frags straight from global) + silu + h-stats + conv2 ----
__global__ __launch_bounds__(256) void k2(const unsigned short* __restrict__ xb16,
                                          const unsigned short* __restrict__ a1,
                                          const unsigned short* __restrict__ a2,
                                          float* __restrict__ wsf,
                                          float* __restrict__ out) {
  __shared__ __align__(16) unsigned char tileH[128 * 128];
  __shared__ float red[8];
  __shared__ float c1s[64];
  const int tid = threadIdx.x;
  const int l = tid & 63, w = tid >> 6;
  const int s = blockIdx.y;
  const int ptile = blockIdx.x * 128;
  const unsigned short* xo = xb16 + (size_t)s * CH * HW;

  const float m1 = wsf[16 + s] / NPIXF;
  const float rs1 = rsqrtf(wsf[32 + s] / NPIXF - m1 * m1 + 1e-6f);
  if (tid < 64) c1s[tid] = wsf[192 + tid] - rs1 * m1 * wsf[128 + tid];

  // B-fragments for both pixel groups, straight from global (coalesced 16B/lane)
  bf16x8 bfr[2][2];
#pragma unroll
  for (int nf = 0; nf < 2; ++nf) {
    const int pl = w * 32 + nf * 16 + (l & 15);
#pragma unroll
    for (int ks = 0; ks < 2; ++ks)
      bfr[nf][ks] = *(const bf16x8*)(xo + (size_t)(ptile + pl) * CH +
                                     ks * 32 + (l >> 4) * 8);
  }

  bf16x8 af[4][2];
#pragma unroll
  for (int mf = 0; mf < 4; ++mf)
#pragma unroll
    for (int ks = 0; ks < 2; ++ks)
      af[mf][ks] = *(const bf16x8*)((const unsigned char*)a1 +
                     (mf * 16 + (l & 15)) * 128 + ks * 64 + (l >> 4) * 16);
  __syncthreads();  // c1s ready

  // phase A: t = A1*x, h = silu(rs1*t + c1), h-stats, h -> tileH
  float hs = 0.f, hq = 0.f;
#pragma unroll
  for (int nf = 0; nf < 2; ++nf) {
    const int pl = w * 32 + nf * 16 + (l & 15);
#pragma unroll
    for (int mf = 0; mf < 4; ++mf) {
      f32x4 acc = {0.f, 0.f, 0.f, 0.f};
      acc = __builtin_amdgcn_mfma_f32_16x16x32_bf16(af[mf][0], bfr[nf][0], acc, 0, 0, 0);
      acc = __builtin_amdgcn_mfma_f32_16x16x32_bf16(af[mf][1], bfr[nf][1], acc, 0, 0, 0);
      const int o0 = mf * 16 + (l >> 4) * 4;
      short4v hv;
#pragma unroll
      for (int r = 0; r < 4; ++r) {
        float z = rs1 * acc[r] + c1s[o0 + r];
        float hh = z / (1.f + __expf(-z));
        hs += hh; hq += hh * hh;
        hv[r] = (short)f2bf(hh);
      }
      *(short4v*)(tileH + pl * 128 + swz(pl, o0 >> 3) * 16 + (o0 & 7) * 2) = hv;
    }
  }
  __syncthreads();

  // phase B: y = A2*h -> raw out (rescaled by k3)
  bf16x8 a2f[2];
#pragma unroll
  for (int ks = 0; ks < 2; ++ks)
    a2f[ks] = *(const bf16x8*)((const unsigned char*)a2 +
                 (l & 15) * 128 + ks * 64 + (l >> 4) * 16);
  float* ob = out + (size_t)s * 6 * HW;
#pragma unroll
  for (int nf = 0; nf < 2; ++nf) {
    const int pl = w * 32 + nf * 16 + (l & 15);
    const int p = ptile + pl;
    bf16x8 hfr[2];
#pragma unroll
    for (int ks = 0; ks < 2; ++ks) {
      int cc = ks * 4 + (l >> 4);
      hfr[ks] = *(const bf16x8*)(tileH + pl * 128 + swz(pl, cc) * 16);
    }
    f32x4 acc = {0.f, 0.f, 0.f, 0.f};
    acc = __builtin_amdgcn_mfma_f32_16x16x32_bf16(a2f[0], hfr[0], acc, 0, 0, 0);
    acc = __builtin_amdgcn_mfma_f32_16x16x32_bf16(a2f[1], hfr[1], acc, 0, 0, 0);
    const int ob0 = (l >> 4) * 4;
#pragma unroll
    for (int r = 0; r < 4; ++r) {
      int o = ob0 + r;
      if (o < 6) ob[(size_t)o * HW + p] = acc[r];
    }
  }

#pragma unroll
  for (int off = 32; off > 0; off >>= 1) {
    hs += __shfl_down(hs, off, 64);
    hq += __shfl_down(hq, off, 64);
  }
  if (l == 0) { red[w] = hs; red[4 + w] = hq; }
  __syncthreads();
  if (tid == 0) {
    atomicAdd(wsf + 48 + s, red[0] + red[1] + red[2] + red[3]);
    atomicAdd(wsf + 64 + s, red[4] + red[5] + red[6] + red[7]);
  }
}

// ---- k3: out = rs2*out + c2[o]  (in-place, elementwise) ----
__global__ __launch_bounds__(256) void k3(float* __restrict__ out,
                                          const float* __restrict__ wsf) {
  const int s = blockIdx.y;
  const float m2 = wsf[48 + s] / NPIXF;
  const float rs2 = rsqrtf(wsf[64 + s] / NPIXF - m2 * m2 + 1e-6f);
  float* ob = out + (size_t)s * 6 * HW;
#pragma unroll
  for (int it = 0; it < 4; ++it) {
    int f4 = blockIdx.x * 256 + threadIdx.x + it * 24576;  // < 98304
    int o = f4 >> 14;  // 16384 f32x4 per output channel
    float c2 = wsf[272 + o] - rs2 * m2 * wsf[256 + o];
    f32x4* p = (f32x4*)ob + f4;
    f32x4 v = *p;
#pragma unroll
    for (int i = 0; i < 4; ++i) v[i] = rs2 * v[i] + c2;
    *p = v;
  }
}

extern "C" void kernel_launch(void* const* d_in, const int* in_sizes, int n_in,
                              void* d_out, int out_size, void* d_ws, size_t ws_size,
                              hipStream_t stream) {
  const float* x  = (const float*)d_in[0];
  const float* s1 = (const float*)d_in[1];
  const float* g1 = (const float*)d_in[2];
  const float* w1 = (const float*)d_in[3];
  const float* b1 = (const float*)d_in[4];
  const float* s2 = (const float*)d_in[5];
  const float* g2 = (const float*)d_in[6];
  const float* w2 = (const float*)d_in[7];
  const float* b2 = (const float*)d_in[8];
  float* out = (float*)d_out;
  float* wsf = (float*)d_ws;
  unsigned short* a1   = (unsigned short*)((char*)d_ws + 2048);
  unsigned short* a2   = (unsigned short*)((char*)d_ws + 10240);
  unsigned short* xb16 = (unsigned short*)((char*)d_ws + 16384);

  const size_t need = 16384u + (size_t)16 * CH * HW * sizeof(unsigned short);
  if (ws_size < need) return;

  k_pre<<<1, 256, 0, stream>>>(w1, b1, s1, g1, w2, b2, s2, g2, wsf, a1, a2);
  k1<<<dim3(256, 16), 256, 0, stream>>>(x, wsf, xb16);
  k2<<<dim3(512, 16), 256, 0, stream>>>(xb16, a1, a2, wsf, out);
  k3<<<dim3(96, 16), 256, 0, stream>>>(out, wsf);
}

// Round 7
// 219.883 us; speedup vs baseline: 1.0060x; 1.0060x over previous
//
#include <hip/hip_runtime.h>

#define HW 65536
#define CH 64
#define NPIXF 4194304.0f

typedef __attribute__((ext_vector_type(8))) short short8;
typedef __attribute__((ext_vector_type(4))) short short4v;
typedef __attribute__((ext_vector_type(8))) __bf16 bf16x8;
typedef __attribute__((ext_vector_type(4))) float f32x4;

__device__ __forceinline__ unsigned short f2bf(float f) {
  unsigned int u = __builtin_bit_cast(unsigned int, f);
  u += 0x7FFFu + ((u >> 16) & 1u);
  return (unsigned short)(u >> 16);
}
__device__ __forceinline__ int swz(int p, int cc) { return cc ^ ((p ^ (p >> 3)) & 7); }

// ws float layout: [16..31]=sum_x [32..47]=sumsq_x [48..63]=sum_h [64..79]=sumsq_h
//                  [128..191]=u1  [192..255]=v1    [256..271]=u2  [272..287]=v2
// bytes: a1 bf16[64][64] @2048, a2 bf16[16][64] @10240,
//        xb16 @16384: bf16 [sample][p][64c]  (pixel-major, MFMA-B-fragment order)

// ---- k_pre: weight prep + zero stat accumulators (1 block, 256 thr) ----
__global__ __launch_bounds__(256) void k_pre(
    const float* __restrict__ w1, const float* __restrict__ b1,
    const float* __restrict__ s1, const float* __restrict__ gb1,
    const float* __restrict__ w2, const float* __restrict__ b2,
    const float* __restrict__ s2, const float* __restrict__ gb2,
    float* __restrict__ wsf,
    unsigned short* __restrict__ a1, unsigned short* __restrict__ a2) {
  const int tid = threadIdx.x;
  {
    int o = tid >> 2, q = tid & 3;
    float u = 0.f, v = 0.f;
    unsigned short loc[16];
#pragma unroll
    for (int i = 0; i < 16; ++i) {
      int c = q * 16 + i;
      float w = w1[o * 64 + c];
      float wsc = w * s1[c];
      loc[i] = f2bf(wsc);
      u += wsc;
      v += w * gb1[c];
    }
    *(short8*)(a1 + o * 64 + q * 16) = *(short8*)loc;
    *(short8*)(a1 + o * 64 + q * 16 + 8) = *(short8*)(loc + 8);
    u += __shfl_xor(u, 1, 64); u += __shfl_xor(u, 2, 64);
    v += __shfl_xor(v, 1, 64); v += __shfl_xor(v, 2, 64);
    if (q == 0) { wsf[128 + o] = u; wsf[192 + o] = b1[o] + v; }
  }
  if (tid < 64) {
    int o = tid >> 2, q = tid & 3;
    float u = 0.f, v = 0.f;
    unsigned short loc[16];
#pragma unroll
    for (int i = 0; i < 16; ++i) {
      int c = q * 16 + i;
      float w = (o < 6) ? w2[o * 64 + c] : 0.f;
      float wsc = w * s2[c];
      loc[i] = f2bf(wsc);
      u += wsc;
      v += w * gb2[c];
    }
    *(short8*)(a2 + o * 64 + q * 16) = *(short8*)loc;
    *(short8*)(a2 + o * 64 + q * 16 + 8) = *(short8*)(loc + 8);
    u += __shfl_xor(u, 1, 64); u += __shfl_xor(u, 2, 64);
    v += __shfl_xor(v, 1, 64); v += __shfl_xor(v, 2, 64);
    if (q == 0) { wsf[256 + o] = u; wsf[272 + o] = ((o < 6) ? b2[o] : 0.f) + v; }
  }
  if (tid >= 192) wsf[16 + (tid - 192)] = 0.f;  // zero 64 stat slots
}

// ---- k1: x stats + bf16 convert; transpose via LDS; coalesced xb16 stores ----
__global__ __launch_bounds__(256) void k1(const float* __restrict__ x,
                                          float* __restrict__ wsf,
                                          unsigned short* __restrict__ xb16) {
  __shared__ __align__(16) unsigned char tile[256 * 128];  // [256 px][64c] bf16, swizzled
  __shared__ float red[8];
  const int tid = threadIdx.x;
  const int l = tid & 63, w = tid >> 6;
  const int b = blockIdx.y;
  const int p0 = blockIdx.x * 256;          // 256 pixels per block
  const float* xs = x + (size_t)b * CH * HW;
  unsigned short* xo = xb16 + (size_t)b * CH * HW;

  const int c0 = (tid >> 5) * 8;            // 8 channels per thread
  const int px = (tid & 31) * 8;            // 8 block-local pixels per thread

  f32x4 va[8], vb[8];
  const float* base = xs + (size_t)c0 * HW + p0 + px;
#pragma unroll
  for (int i = 0; i < 8; ++i) {
    va[i] = *(const f32x4*)(base + (size_t)i * HW);
    vb[i] = *(const f32x4*)(base + (size_t)i * HW + 4);
  }

  float s = 0.f, q = 0.f;
#pragma unroll
  for (int i = 0; i < 8; ++i)
#pragma unroll
    for (int j = 0; j < 4; ++j) {
      float f0 = va[i][j]; s += f0; q += f0 * f0;
      float f1 = vb[i][j]; s += f1; q += f1 * f1;
    }

  // convert + transpose into LDS: one pixel's 8 channels per short8
#pragma unroll
  for (int dp = 0; dp < 4; ++dp) {
    int p = px + dp;
    short8 w8;
#pragma unroll
    for (int i = 0; i < 8; ++i) w8[i] = (short)f2bf(va[i][dp]);
    *(short8*)(tile + p * 128 + swz(p, c0 >> 3) * 16) = w8;
  }
#pragma unroll
  for (int dp = 0; dp < 4; ++dp) {
    int p = px + 4 + dp;
    short8 w8;
#pragma unroll
    for (int i = 0; i < 8; ++i) w8[i] = (short)f2bf(vb[i][dp]);
    *(short8*)(tile + p * 128 + swz(p, c0 >> 3) * 16) = w8;
  }
  __syncthreads();

  // coalesced store: thread t -> pixel t>>3, chunk t&7; 1KB contiguous per wave
  const int cc = tid & 7;
#pragma unroll
  for (int it = 0; it < 8; ++it) {
    int pp = it * 32 + (tid >> 3);
    short8 v = *(const short8*)(tile + pp * 128 + swz(pp, cc) * 16);
    *(short8*)(xo + (size_t)(p0 + pp) * CH + cc * 8) = v;
  }

#pragma unroll
  for (int off = 32; off > 0; off >>= 1) {
    s += __shfl_down(s, off, 64);
    q += __shfl_down(q, off, 64);
  }
  if (l == 0) { red[w] = s; red[4 + w] = q; }
  __syncthreads();
  if (tid == 0) {
    atomicAdd(wsf + 16 + b, red[0] + red[1] + red[2] + red[3]);
    atomicAdd(wsf + 32 + b, red[4] + red[5] + red[6] + red[7]);
  }
}

// ---- k2: conv1 (B-frags straight from global) + silu + h-stats + conv2 ----
__global__ __launch_bounds__(256) void k2(const unsigned short* __restrict__ xb16,
                                          const unsigned short* __restrict__ a1,
                                          const unsigned short* __restrict__ a2,
                                          float* __restrict__ wsf,
                                          float* __restrict__ out) {
  __shared__ __align__(16) unsigned char tileH[128 * 128];
  __shared__ float red[8];
  __shared__ float c1s[64];
  const int tid = threadIdx.x;
  const int l = tid & 63, w = tid >> 6;
  const int s = blockIdx.y;
  const int ptile = blockIdx.x * 128;
  const unsigned short* xo = xb16 + (size_t)s * CH * HW;

  const float m1 = wsf[16 + s] / NPIXF;
  const float rs1 = rsqrtf(wsf[32 + s] / NPIXF - m1 * m1 + 1e-6f);
  if (tid < 64) c1s[tid] = wsf[192 + tid] - rs1 * m1 * wsf[128 + tid];

  // B-fragments for both pixel groups, straight from global (16B/lane)
  bf16x8 bfr[2][2];
#pragma unroll
  for (int nf = 0; nf < 2; ++nf) {
    const int pl = w * 32 + nf * 16 + (l & 15);
#pragma unroll
    for (int ks = 0; ks < 2; ++ks)
      bfr[nf][ks] = *(const bf16x8*)(xo + (size_t)(ptile + pl) * CH +
                                     ks * 32 + (l >> 4) * 8);
  }

  bf16x8 af[4][2];
#pragma unroll
  for (int mf = 0; mf < 4; ++mf)
#pragma unroll
    for (int ks = 0; ks < 2; ++ks)
      af[mf][ks] = *(const bf16x8*)((const unsigned char*)a1 +
                     (mf * 16 + (l & 15)) * 128 + ks * 64 + (l >> 4) * 16);
  __syncthreads();  // c1s ready

  // phase A: t = A1*x, h = silu(rs1*t + c1), h-stats, h -> tileH
  float hs = 0.f, hq = 0.f;
#pragma unroll
  for (int nf = 0; nf < 2; ++nf) {
    const int pl = w * 32 + nf * 16 + (l & 15);
#pragma unroll
    for (int mf = 0; mf < 4; ++mf) {
      f32x4 acc = {0.f, 0.f, 0.f, 0.f};
      acc = __builtin_amdgcn_mfma_f32_16x16x32_bf16(af[mf][0], bfr[nf][0], acc, 0, 0, 0);
      acc = __builtin_amdgcn_mfma_f32_16x16x32_bf16(af[mf][1], bfr[nf][1], acc, 0, 0, 0);
      const int o0 = mf * 16 + (l >> 4) * 4;
      short4v hv;
#pragma unroll
      for (int r = 0; r < 4; ++r) {
        float z = rs1 * acc[r] + c1s[o0 + r];
        float hh = z / (1.f + __expf(-z));
        hs += hh; hq += hh * hh;
        hv[r] = (short)f2bf(hh);
      }
      *(short4v*)(tileH + pl * 128 + swz(pl, o0 >> 3) * 16 + (o0 & 7) * 2) = hv;
    }
  }
  __syncthreads();

  // phase B: y = A2*h -> raw out (rescaled by k3)
  bf16x8 a2f[2];
#pragma unroll
  for (int ks = 0; ks < 2; ++ks)
    a2f[ks] = *(const bf16x8*)((const unsigned char*)a2 +
                 (l & 15) * 128 + ks * 64 + (l >> 4) * 16);
  float* ob = out + (size_t)s * 6 * HW;
#pragma unroll
  for (int nf = 0; nf < 2; ++nf) {
    const int pl = w * 32 + nf * 16 + (l & 15);
    const int p = ptile + pl;
    bf16x8 hfr[2];
#pragma unroll
    for (int ks = 0; ks < 2; ++ks) {
      int cc = ks * 4 + (l >> 4);
      hfr[ks] = *(const bf16x8*)(tileH + pl * 128 + swz(pl, cc) * 16);
    }
    f32x4 acc = {0.f, 0.f, 0.f, 0.f};
    acc = __builtin_amdgcn_mfma_f32_16x16x32_bf16(a2f[0], hfr[0], acc, 0, 0, 0);
    acc = __builtin_amdgcn_mfma_f32_16x16x32_bf16(a2f[1], hfr[1], acc, 0, 0, 0);
    const int ob0 = (l >> 4) * 4;
#pragma unroll
    for (int r = 0; r < 4; ++r) {
      int o = ob0 + r;
      if (o < 6) ob[(size_t)o * HW + p] = acc[r];
    }
  }

#pragma unroll
  for (int off = 32; off > 0; off >>= 1) {
    hs += __shfl_down(hs, off, 64);
    hq += __shfl_down(hq, off, 64);
  }
  if (l == 0) { red[w] = hs; red[4 + w] = hq; }
  __syncthreads();
  if (tid == 0) {
    atomicAdd(wsf + 48 + s, red[0] + red[1] + red[2] + red[3]);
    atomicAdd(wsf + 64 + s, red[4] + red[5] + red[6] + red[7]);
  }
}

// ---- k3: out = rs2*out + c2[o]  (in-place, elementwise) ----
__global__ __launch_bounds__(256) void k3(float* __restrict__ out,
                                          const float* __restrict__ wsf) {
  const int s = blockIdx.y;
  const float m2 = wsf[48 + s] / NPIXF;
  const float rs2 = rsqrtf(wsf[64 + s] / NPIXF - m2 * m2 + 1e-6f);
  float* ob = out + (size_t)s * 6 * HW;
#pragma unroll
  for (int it = 0; it < 4; ++it) {
    int f4 = blockIdx.x * 256 + threadIdx.x + it * 24576;  // < 98304
    int o = f4 >> 14;  // 16384 f32x4 per output channel
    float c2 = wsf[272 + o] - rs2 * m2 * wsf[256 + o];
    f32x4* p = (f32x4*)ob + f4;
    f32x4 v = *p;
#pragma unroll
    for (int i = 0; i < 4; ++i) v[i] = rs2 * v[i] + c2;
    *p = v;
  }
}

extern "C" void kernel_launch(void* const* d_in, const int* in_sizes, int n_in,
                              void* d_out, int out_size, void* d_ws, size_t ws_size,
                              hipStream_t stream) {
  const float* x  = (const float*)d_in[0];
  const float* s1 = (const float*)d_in[1];
  const float* g1 = (const float*)d_in[2];
  const float* w1 = (const float*)d_in[3];
  const float* b1 = (const float*)d_in[4];
  const float* s2 = (const float*)d_in[5];
  const float* g2 = (const float*)d_in[6];
  const float* w2 = (const float*)d_in[7];
  const float* b2 = (const float*)d_in[8];
  float* out = (float*)d_out;
  float* wsf = (float*)d_ws;
  unsigned short* a1   = (unsigned short*)((char*)d_ws + 2048);
  unsigned short* a2   = (unsigned short*)((char*)d_ws + 10240);
  unsigned short* xb16 = (unsigned short*)((char*)d_ws + 16384);

  const size_t need = 16384u + (size_t)16 * CH * HW * sizeof(unsigned short);
  if (ws_size < need) return;

  k_pre<<<1, 256, 0, stream>>>(w1, b1, s1, g1, w2, b2, s2, g2, wsf, a1, a2);
  k1<<<dim3(256, 16), 256, 0, stream>>>(x, wsf, xb16);
  k2<<<dim3(512, 16), 256, 0, stream>>>(xb16, a1, a2, wsf, out);
  k3<<<dim3(96, 16), 256, 0, stream>>>(out, wsf);
}

// Round 8
// 155.047 us; speedup vs baseline: 1.4267x; 1.4182x over previous
//
#include <hip/hip_runtime.h>

#define HW 65536
#define CH 64
#define NPIXF 4194304.0f

typedef __attribute__((ext_vector_type(8))) short short8;
typedef __attribute__((ext_vector_type(4))) short short4v;
typedef __attribute__((ext_vector_type(8))) __bf16 bf16x8;
typedef __attribute__((ext_vector_type(4))) float f32x4;

__device__ __forceinline__ unsigned short f2bf(float f) {
  unsigned int u = __builtin_bit_cast(unsigned int, f);
  u += 0x7FFFu + ((u >> 16) & 1u);
  return (unsigned short)(u >> 16);
}
__device__ __forceinline__ int swz(int p, int cc) { return cc ^ ((p ^ (p >> 3)) & 7); }

// ws layout (floats):
//   stats: wsf[16*s+0]=sum_x  +1=sumsq_x  +2=sum_h  +3=sumsq_h   (one 64B line per sample, memset-zeroed)
//   consts: u1=wsf[256..319]  v1=wsf[320..383]  u2=wsf[384..399]  v2=wsf[400..415]
// bytes: a1 bf16[64][64] @2048, a2 bf16[16][64] @10240.  total need = 16384 B.

// ---- k1: x stats (streaming); block (0,0) additionally preps weights ----
__global__ __launch_bounds__(256) void k1(
    const float* __restrict__ x,
    const float* __restrict__ w1, const float* __restrict__ b1,
    const float* __restrict__ s1, const float* __restrict__ gb1,
    const float* __restrict__ w2, const float* __restrict__ b2,
    const float* __restrict__ s2, const float* __restrict__ gb2,
    float* __restrict__ wsf,
    unsigned short* __restrict__ a1, unsigned short* __restrict__ a2) {
  __shared__ float red[8];
  const int tid = threadIdx.x;
  const int l = tid & 63, w = tid >> 6;
  const int b = blockIdx.y;

  // weight prep on one block only (raceless: only k2/k3 read these)
  if (blockIdx.x == 0 && b == 0) {
    {
      int o = tid >> 2, q = tid & 3;
      float u = 0.f, v = 0.f;
      unsigned short loc[16];
#pragma unroll
      for (int i = 0; i < 16; ++i) {
        int c = q * 16 + i;
        float wv = w1[o * 64 + c];
        float wsc = wv * s1[c];
        loc[i] = f2bf(wsc);
        u += wsc;
        v += wv * gb1[c];
      }
      *(short8*)(a1 + o * 64 + q * 16) = *(short8*)loc;
      *(short8*)(a1 + o * 64 + q * 16 + 8) = *(short8*)(loc + 8);
      u += __shfl_xor(u, 1, 64); u += __shfl_xor(u, 2, 64);
      v += __shfl_xor(v, 1, 64); v += __shfl_xor(v, 2, 64);
      if (q == 0) { wsf[256 + o] = u; wsf[320 + o] = b1[o] + v; }
    }
    if (tid < 64) {
      int o = tid >> 2, q = tid & 3;
      float u = 0.f, v = 0.f;
      unsigned short loc[16];
#pragma unroll
      for (int i = 0; i < 16; ++i) {
        int c = q * 16 + i;
        float wv = (o < 6) ? w2[o * 64 + c] : 0.f;
        float wsc = wv * s2[c];
        loc[i] = f2bf(wsc);
        u += wsc;
        v += wv * gb2[c];
      }
      *(short8*)(a2 + o * 64 + q * 16) = *(short8*)loc;
      *(short8*)(a2 + o * 64 + q * 16 + 8) = *(short8*)(loc + 8);
      u += __shfl_xor(u, 1, 64); u += __shfl_xor(u, 2, 64);
      v += __shfl_xor(v, 1, 64); v += __shfl_xor(v, 2, 64);
      if (q == 0) { wsf[384 + o] = u; wsf[400 + o] = ((o < 6) ? b2[o] : 0.f) + v; }
    }
  }

  // streaming stats: block covers 128KB contiguous of sample b
  const f32x4* xb = (const f32x4*)(x + (size_t)b * CH * HW);
  const f32x4* p = xb + (size_t)blockIdx.x * 8192 + tid;
  float s = 0.f, q = 0.f;
#pragma unroll
  for (int it = 0; it < 32; ++it) {
    f32x4 v = p[it * 256];
#pragma unroll
    for (int i = 0; i < 4; ++i) { float f = v[i]; s += f; q += f * f; }
  }
#pragma unroll
  for (int off = 32; off > 0; off >>= 1) {
    s += __shfl_down(s, off, 64);
    q += __shfl_down(q, off, 64);
  }
  if (l == 0) { red[w] = s; red[4 + w] = q; }
  __syncthreads();
  if (tid == 0) {
    atomicAdd(wsf + 16 * b + 0, red[0] + red[1] + red[2] + red[3]);
    atomicAdd(wsf + 16 * b + 1, red[4] + red[5] + red[6] + red[7]);
  }
}

// ---- k2: read x (REVERSE order -> L3 hits), conv1 MFMA, silu+h-stats, conv2, raw y ----
__global__ __launch_bounds__(256) void k2(const float* __restrict__ x,
                                          const unsigned short* __restrict__ a1,
                                          const unsigned short* __restrict__ a2,
                                          float* __restrict__ wsf,
                                          float* __restrict__ out) {
  __shared__ __align__(16) unsigned char tileX[128 * 128];
  __shared__ __align__(16) unsigned char tileH[128 * 128];
  __shared__ float red[8];
  __shared__ float c1s[64];
  const int tid = threadIdx.x;
  const int l = tid & 63, w = tid >> 6;
  const int s = 15 - blockIdx.y;                 // reverse sample order
  const int ptile = (511 - blockIdx.x) * 128;    // reverse tile order
  const float* xb = x + (size_t)s * CH * HW;

  const float m1 = wsf[16 * s + 0] / NPIXF;
  const float rs1 = rsqrtf(wsf[16 * s + 1] / NPIXF - m1 * m1 + 1e-6f);
  if (tid < 64) c1s[tid] = wsf[320 + tid] - rs1 * m1 * wsf[256 + tid];

  // load x tile: 8 channels x 4 pixels per thread, transpose into tileX [p][c]
  const int c0 = (tid >> 5) * 8;
  const int p4 = (tid & 31) * 4;
  f32x4 v[8];
  const float* base = xb + (size_t)c0 * HW + ptile + p4;
#pragma unroll
  for (int i = 0; i < 8; ++i) v[i] = *(const f32x4*)(base + (size_t)i * HW);

  bf16x8 af[4][2];
#pragma unroll
  for (int mf = 0; mf < 4; ++mf)
#pragma unroll
    for (int ks = 0; ks < 2; ++ks)
      af[mf][ks] = *(const bf16x8*)((const unsigned char*)a1 +
                     (mf * 16 + (l & 15)) * 128 + ks * 64 + (l >> 4) * 16);

#pragma unroll
  for (int dp = 0; dp < 4; ++dp) {
    int p = p4 + dp;
    short8 w8;
#pragma unroll
    for (int i = 0; i < 8; ++i) w8[i] = (short)f2bf(v[i][dp]);
    *(short8*)(tileX + p * 128 + swz(p, c0 >> 3) * 16) = w8;
  }
  __syncthreads();

  // phase A: t = A1*x, h = silu(rs1*t + c1), h-stats, h -> tileH
  float hs = 0.f, hq = 0.f;
#pragma unroll
  for (int nf = 0; nf < 2; ++nf) {
    const int pl = w * 32 + nf * 16 + (l & 15);
    bf16x8 bfr[2];
#pragma unroll
    for (int ks = 0; ks < 2; ++ks) {
      int cc = ks * 4 + (l >> 4);
      bfr[ks] = *(const bf16x8*)(tileX + pl * 128 + swz(pl, cc) * 16);
    }
#pragma unroll
    for (int mf = 0; mf < 4; ++mf) {
      f32x4 acc = {0.f, 0.f, 0.f, 0.f};
      acc = __builtin_amdgcn_mfma_f32_16x16x32_bf16(af[mf][0], bfr[0], acc, 0, 0, 0);
      acc = __builtin_amdgcn_mfma_f32_16x16x32_bf16(af[mf][1], bfr[1], acc, 0, 0, 0);
      const int o0 = mf * 16 + (l >> 4) * 4;
      short4v hv;
#pragma unroll
      for (int r = 0; r < 4; ++r) {
        float z = rs1 * acc[r] + c1s[o0 + r];
        float hh = z / (1.f + __expf(-z));
        hs += hh; hq += hh * hh;
        hv[r] = (short)f2bf(hh);
      }
      *(short4v*)(tileH + pl * 128 + swz(pl, o0 >> 3) * 16 + (o0 & 7) * 2) = hv;
    }
  }
  __syncthreads();

  // phase B: y = A2*h -> raw out (rescaled by k3)
  bf16x8 a2f[2];
#pragma unroll
  for (int ks = 0; ks < 2; ++ks)
    a2f[ks] = *(const bf16x8*)((const unsigned char*)a2 +
                 (l & 15) * 128 + ks * 64 + (l >> 4) * 16);
  float* ob = out + (size_t)s * 6 * HW;
#pragma unroll
  for (int nf = 0; nf < 2; ++nf) {
    const int pl = w * 32 + nf * 16 + (l & 15);
    const int p = ptile + pl;
    bf16x8 hfr[2];
#pragma unroll
    for (int ks = 0; ks < 2; ++ks) {
      int cc = ks * 4 + (l >> 4);
      hfr[ks] = *(const bf16x8*)(tileH + pl * 128 + swz(pl, cc) * 16);
    }
    f32x4 acc = {0.f, 0.f, 0.f, 0.f};
    acc = __builtin_amdgcn_mfma_f32_16x16x32_bf16(a2f[0], hfr[0], acc, 0, 0, 0);
    acc = __builtin_amdgcn_mfma_f32_16x16x32_bf16(a2f[1], hfr[1], acc, 0, 0, 0);
    const int ob0 = (l >> 4) * 4;
#pragma unroll
    for (int r = 0; r < 4; ++r) {
      int o = ob0 + r;
      if (o < 6) ob[(size_t)o * HW + p] = acc[r];
    }
  }

#pragma unroll
  for (int off = 32; off > 0; off >>= 1) {
    hs += __shfl_down(hs, off, 64);
    hq += __shfl_down(hq, off, 64);
  }
  if (l == 0) { red[w] = hs; red[4 + w] = hq; }
  __syncthreads();
  if (tid == 0) {
    atomicAdd(wsf + 16 * s + 2, red[0] + red[1] + red[2] + red[3]);
    atomicAdd(wsf + 16 * s + 3, red[4] + red[5] + red[6] + red[7]);
  }
}

// ---- k3: out = rs2*out + c2[o]  (in-place, elementwise; reverse order too) ----
__global__ __launch_bounds__(256) void k3(float* __restrict__ out,
                                          const float* __restrict__ wsf) {
  const int s = 15 - blockIdx.y;
  const float m2 = wsf[16 * s + 2] / NPIXF;
  const float rs2 = rsqrtf(wsf[16 * s + 3] / NPIXF - m2 * m2 + 1e-6f);
  float* ob = out + (size_t)s * 6 * HW;
#pragma unroll
  for (int it = 0; it < 4; ++it) {
    int f4 = blockIdx.x * 256 + threadIdx.x + it * 24576;  // < 98304
    int o = f4 >> 14;  // 16384 f32x4 per output channel
    float c2 = wsf[400 + o] - rs2 * m2 * wsf[384 + o];
    f32x4* p = (f32x4*)ob + f4;
    f32x4 v = *p;
#pragma unroll
    for (int i = 0; i < 4; ++i) v[i] = rs2 * v[i] + c2;
    *p = v;
  }
}

extern "C" void kernel_launch(void* const* d_in, const int* in_sizes, int n_in,
                              void* d_out, int out_size, void* d_ws, size_t ws_size,
                              hipStream_t stream) {
  const float* x  = (const float*)d_in[0];
  const float* s1 = (const float*)d_in[1];
  const float* g1 = (const float*)d_in[2];
  const float* w1 = (const float*)d_in[3];
  const float* b1 = (const float*)d_in[4];
  const float* s2 = (const float*)d_in[5];
  const float* g2 = (const float*)d_in[6];
  const float* w2 = (const float*)d_in[7];
  const float* b2 = (const float*)d_in[8];
  float* out = (float*)d_out;
  float* wsf = (float*)d_ws;
  unsigned short* a1 = (unsigned short*)((char*)d_ws + 2048);
  unsigned short* a2 = (unsigned short*)((char*)d_ws + 10240);

  if (ws_size < 16384) return;

  hipMemsetAsync(d_ws, 0, 1024, stream);  // zero per-sample stat lines
  k1<<<dim3(128, 16), 256, 0, stream>>>(x, w1, b1, s1, g1, w2, b2, s2, g2, wsf, a1, a2);
  k2<<<dim3(512, 16), 256, 0, stream>>>(x, a1, a2, wsf, out);
  k3<<<dim3(96, 16), 256, 0, stream>>>(out, wsf);
}

// Round 9
// 154.799 us; speedup vs baseline: 1.4290x; 1.0016x over previous
//
#include <hip/hip_runtime.h>

#define HW 65536
#define CH 64
#define NPIXF 4194304.0f

typedef __attribute__((ext_vector_type(8))) short short8;
typedef __attribute__((ext_vector_type(4))) short short4v;
typedef __attribute__((ext_vector_type(8))) __bf16 bf16x8;
typedef __attribute__((ext_vector_type(4))) float f32x4;

__device__ __forceinline__ unsigned short f2bf(float f) {
  unsigned int u = __builtin_bit_cast(unsigned int, f);
  u += 0x7FFFu + ((u >> 16) & 1u);
  return (unsigned short)(u >> 16);
}
__device__ __forceinline__ short cvt1(float f) {
  return __builtin_bit_cast(short, (__bf16)f);  // compiler fuses pairs to v_cvt_pk_bf16_f32
}
__device__ __forceinline__ int swz(int p, int cc) { return cc ^ ((p ^ (p >> 3)) & 7); }

// ws layout (floats):
//   stats: wsf[16*s+0]=sum_x +1=sumsq_x +2=sum_h +3=sumsq_h  (64B line per sample, memset-zeroed)
//   consts: u1=wsf[256..319]  v1=wsf[320..383]  u2=wsf[384..399]  v2=wsf[400..415]
// bytes: a1 bf16[64][64] @2048, a2 bf16[16][64] @10240.  total need = 16384 B.

// ---- k1: x stats (streaming, full occupancy); block (0,0) preps weights ----
__global__ __launch_bounds__(256, 8) void k1(
    const float* __restrict__ x,
    const float* __restrict__ w1, const float* __restrict__ b1,
    const float* __restrict__ s1, const float* __restrict__ gb1,
    const float* __restrict__ w2, const float* __restrict__ b2,
    const float* __restrict__ s2, const float* __restrict__ gb2,
    float* __restrict__ wsf,
    unsigned short* __restrict__ a1, unsigned short* __restrict__ a2) {
  __shared__ float red[8];
  const int tid = threadIdx.x;
  const int l = tid & 63, w = tid >> 6;
  const int b = blockIdx.y;

  if (blockIdx.x == 0 && b == 0) {
    {
      int o = tid >> 2, q = tid & 3;
      float u = 0.f, v = 0.f;
      unsigned short loc[16];
#pragma unroll
      for (int i = 0; i < 16; ++i) {
        int c = q * 16 + i;
        float wv = w1[o * 64 + c];
        float wsc = wv * s1[c];
        loc[i] = f2bf(wsc);
        u += wsc;
        v += wv * gb1[c];
      }
      *(short8*)(a1 + o * 64 + q * 16) = *(short8*)loc;
      *(short8*)(a1 + o * 64 + q * 16 + 8) = *(short8*)(loc + 8);
      u += __shfl_xor(u, 1, 64); u += __shfl_xor(u, 2, 64);
      v += __shfl_xor(v, 1, 64); v += __shfl_xor(v, 2, 64);
      if (q == 0) { wsf[256 + o] = u; wsf[320 + o] = b1[o] + v; }
    }
    if (tid < 64) {
      int o = tid >> 2, q = tid & 3;
      float u = 0.f, v = 0.f;
      unsigned short loc[16];
#pragma unroll
      for (int i = 0; i < 16; ++i) {
        int c = q * 16 + i;
        float wv = (o < 6) ? w2[o * 64 + c] : 0.f;
        float wsc = wv * s2[c];
        loc[i] = f2bf(wsc);
        u += wsc;
        v += wv * gb2[c];
      }
      *(short8*)(a2 + o * 64 + q * 16) = *(short8*)loc;
      *(short8*)(a2 + o * 64 + q * 16 + 8) = *(short8*)(loc + 8);
      u += __shfl_xor(u, 1, 64); u += __shfl_xor(u, 2, 64);
      v += __shfl_xor(v, 1, 64); v += __shfl_xor(v, 2, 64);
      if (q == 0) { wsf[384 + o] = u; wsf[400 + o] = ((o < 6) ? b2[o] : 0.f) + v; }
    }
  }

  const f32x4* xb = (const f32x4*)(x + (size_t)b * CH * HW);
  const f32x4* p = xb + (size_t)blockIdx.x * 8192 + tid;
  float s = 0.f, q = 0.f;
#pragma unroll
  for (int it = 0; it < 32; ++it) {
    f32x4 v = p[it * 256];
#pragma unroll
    for (int i = 0; i < 4; ++i) { float f = v[i]; s += f; q += f * f; }
  }
#pragma unroll
  for (int off = 32; off > 0; off >>= 1) {
    s += __shfl_down(s, off, 64);
    q += __shfl_down(q, off, 64);
  }
  if (l == 0) { red[w] = s; red[4 + w] = q; }
  __syncthreads();
  if (tid == 0) {
    atomicAdd(wsf + 16 * b + 0, red[0] + red[1] + red[2] + red[3]);
    atomicAdd(wsf + 16 * b + 1, red[4] + red[5] + red[6] + red[7]);
  }
}

// ---- k2: x (reverse, L3-hot) -> conv1 MFMA -> silu+h-stats -> conv2 -> raw y ----
// single 16KB tile; rows w*32..w*32+31 are wave-private in compute phases.
__global__ __launch_bounds__(256, 4) void k2(const float* __restrict__ x,
                                             const unsigned short* __restrict__ a1,
                                             const unsigned short* __restrict__ a2,
                                             const float* __restrict__ wsf,
                                             float* __restrict__ wstat,
                                             float* __restrict__ out) {
  __shared__ __align__(16) unsigned char tile[128 * 128];
  __shared__ float red[8];
  const int tid = threadIdx.x;
  const int l = tid & 63, w = tid >> 6;
  const int s = 15 - blockIdx.y;                 // reverse sample order
  const int ptile = (511 - blockIdx.x) * 128;    // reverse tile order
  const float* xb = x + (size_t)s * CH * HW;

  const float m1 = wsf[16 * s + 0] / NPIXF;
  const float rs1 = rsqrtf(wsf[16 * s + 1] / NPIXF - m1 * m1 + 1e-6f);

  // c1 in registers: thread needs channels o0+r = mf*16 + (l>>4)*4 + r
  float c1r[4][4];
#pragma unroll
  for (int mf = 0; mf < 4; ++mf) {
    const int o0 = mf * 16 + (l >> 4) * 4;
    f32x4 u = *(const f32x4*)(wsf + 256 + o0);
    f32x4 vv = *(const f32x4*)(wsf + 320 + o0);
#pragma unroll
    for (int r = 0; r < 4; ++r) c1r[mf][r] = vv[r] - rs1 * m1 * u[r];
  }

  // weight fragments
  bf16x8 af[4][2];
#pragma unroll
  for (int mf = 0; mf < 4; ++mf)
#pragma unroll
    for (int ks = 0; ks < 2; ++ks)
      af[mf][ks] = *(const bf16x8*)((const unsigned char*)a1 +
                     (mf * 16 + (l & 15)) * 128 + ks * 64 + (l >> 4) * 16);
  bf16x8 a2f[2];
#pragma unroll
  for (int ks = 0; ks < 2; ++ks)
    a2f[ks] = *(const bf16x8*)((const unsigned char*)a2 +
                 (l & 15) * 128 + ks * 64 + (l >> 4) * 16);

  // x tile: 8 ch x 4 px per thread -> cvt -> transpose into tile [p][c]
  const int c0 = (tid >> 5) * 8;
  const int p4 = (tid & 31) * 4;
  f32x4 v[8];
  const float* base = xb + (size_t)c0 * HW + ptile + p4;
#pragma unroll
  for (int i = 0; i < 8; ++i) v[i] = *(const f32x4*)(base + (size_t)i * HW);
#pragma unroll
  for (int dp = 0; dp < 4; ++dp) {
    int p = p4 + dp;
    short8 w8;
#pragma unroll
    for (int i = 0; i < 8; ++i) w8[i] = cvt1(v[i][dp]);
    *(short8*)(tile + p * 128 + swz(p, c0 >> 3) * 16) = w8;
  }
  __syncthreads();  // the only barrier: cross-wave transpose complete

  // pre-read both nf B-fragments (after this, tile rows are wave-private)
  bf16x8 bfr[2][2];
#pragma unroll
  for (int nf = 0; nf < 2; ++nf) {
    const int pl = w * 32 + nf * 16 + (l & 15);
#pragma unroll
    for (int ks = 0; ks < 2; ++ks) {
      int cc = ks * 4 + (l >> 4);
      bfr[nf][ks] = *(const bf16x8*)(tile + pl * 128 + swz(pl, cc) * 16);
    }
  }

  // phase A: t = A1*x, h = silu(rs1*t + c1), h-stats, h -> tile (in place)
  float hs = 0.f, hq = 0.f;
#pragma unroll
  for (int nf = 0; nf < 2; ++nf) {
    const int pl = w * 32 + nf * 16 + (l & 15);
#pragma unroll
    for (int mf = 0; mf < 4; ++mf) {
      f32x4 acc = {0.f, 0.f, 0.f, 0.f};
      acc = __builtin_amdgcn_mfma_f32_16x16x32_bf16(af[mf][0], bfr[nf][0], acc, 0, 0, 0);
      acc = __builtin_amdgcn_mfma_f32_16x16x32_bf16(af[mf][1], bfr[nf][1], acc, 0, 0, 0);
      const int o0 = mf * 16 + (l >> 4) * 4;
      short4v hv;
#pragma unroll
      for (int r = 0; r < 4; ++r) {
        float z = rs1 * acc[r] + c1r[mf][r];
        float hh = z / (1.f + __expf(-z));
        hs += hh; hq += hh * hh;
        hv[r] = cvt1(hh);
      }
      *(short4v*)(tile + pl * 128 + swz(pl, o0 >> 3) * 16 + (o0 & 7) * 2) = hv;
    }
  }
  // no barrier: phase B reads only rows this wave wrote (in-wave LDS ordering)

  // phase B: y = A2*h -> raw out (rescaled by k3)
  float* ob = out + (size_t)s * 6 * HW;
#pragma unroll
  for (int nf = 0; nf < 2; ++nf) {
    const int pl = w * 32 + nf * 16 + (l & 15);
    const int p = ptile + pl;
    bf16x8 hfr[2];
#pragma unroll
    for (int ks = 0; ks < 2; ++ks) {
      int cc = ks * 4 + (l >> 4);
      hfr[ks] = *(const bf16x8*)(tile + pl * 128 + swz(pl, cc) * 16);
    }
    f32x4 acc = {0.f, 0.f, 0.f, 0.f};
    acc = __builtin_amdgcn_mfma_f32_16x16x32_bf16(a2f[0], hfr[0], acc, 0, 0, 0);
    acc = __builtin_amdgcn_mfma_f32_16x16x32_bf16(a2f[1], hfr[1], acc, 0, 0, 0);
    const int ob0 = (l >> 4) * 4;
#pragma unroll
    for (int r = 0; r < 4; ++r) {
      int o = ob0 + r;
      if (o < 6) ob[(size_t)o * HW + p] = acc[r];
    }
  }

#pragma unroll
  for (int off = 32; off > 0; off >>= 1) {
    hs += __shfl_down(hs, off, 64);
    hq += __shfl_down(hq, off, 64);
  }
  if (l == 0) { red[w] = hs; red[4 + w] = hq; }
  __syncthreads();
  if (tid == 0) {
    atomicAdd(wstat + 16 * s + 2, red[0] + red[1] + red[2] + red[3]);
    atomicAdd(wstat + 16 * s + 3, red[4] + red[5] + red[6] + red[7]);
  }
}

// ---- k3: out = rs2*out + c2[o]  (in-place, elementwise; reverse order) ----
__global__ __launch_bounds__(256) void k3(float* __restrict__ out,
                                          const float* __restrict__ wsf) {
  const int s = 15 - blockIdx.y;
  const float m2 = wsf[16 * s + 2] / NPIXF;
  const float rs2 = rsqrtf(wsf[16 * s + 3] / NPIXF - m2 * m2 + 1e-6f);
  float* ob = out + (size_t)s * 6 * HW;
#pragma unroll
  for (int it = 0; it < 4; ++it) {
    int f4 = blockIdx.x * 256 + threadIdx.x + it * 24576;  // < 98304
    int o = f4 >> 14;
    float c2 = wsf[400 + o] - rs2 * m2 * wsf[384 + o];
    f32x4* p = (f32x4*)ob + f4;
    f32x4 v = *p;
#pragma unroll
    for (int i = 0; i < 4; ++i) v[i] = rs2 * v[i] + c2;
    *p = v;
  }
}

extern "C" void kernel_launch(void* const* d_in, const int* in_sizes, int n_in,
                              void* d_out, int out_size, void* d_ws, size_t ws_size,
                              hipStream_t stream) {
  const float* x  = (const float*)d_in[0];
  const float* s1 = (const float*)d_in[1];
  const float* g1 = (const float*)d_in[2];
  const float* w1 = (const float*)d_in[3];
  const float* b1 = (const float*)d_in[4];
  const float* s2 = (const float*)d_in[5];
  const float* g2 = (const float*)d_in[6];
  const float* w2 = (const float*)d_in[7];
  const float* b2 = (const float*)d_in[8];
  float* out = (float*)d_out;
  float* wsf = (float*)d_ws;
  unsigned short* a1 = (unsigned short*)((char*)d_ws + 2048);
  unsigned short* a2 = (unsigned short*)((char*)d_ws + 10240);

  if (ws_size < 16384) return;

  hipMemsetAsync(d_ws, 0, 1024, stream);  // zero per-sample stat lines
  k1<<<dim3(128, 16), 256, 0, stream>>>(x, w1, b1, s1, g1, w2, b2, s2, g2, wsf, a1, a2);
  k2<<<dim3(512, 16), 256, 0, stream>>>(x, a1, a2, wsf, wsf, out);
  k3<<<dim3(96, 16), 256, 0, stream>>>(out, wsf);
}

// Round 10
// 154.278 us; speedup vs baseline: 1.4338x; 1.0034x over previous
//
#include <hip/hip_runtime.h>

#define HW 65536
#define CH 64
#define NPIXF 4194304.0f

typedef __attribute__((ext_vector_type(8))) short short8;
typedef __attribute__((ext_vector_type(4))) short short4v;
typedef __attribute__((ext_vector_type(8))) __bf16 bf16x8;
typedef __attribute__((ext_vector_type(4))) float f32x4;

__device__ __forceinline__ unsigned short f2bf(float f) {
  unsigned int u = __builtin_bit_cast(unsigned int, f);
  u += 0x7FFFu + ((u >> 16) & 1u);
  return (unsigned short)(u >> 16);
}
__device__ __forceinline__ short cvt1(float f) {
  return __builtin_bit_cast(short, (__bf16)f);  // pairs fuse to v_cvt_pk_bf16_f32
}
__device__ __forceinline__ float fastrcp(float f) {
  return __builtin_amdgcn_rcpf(f);  // v_rcp_f32, ~1 ulp; avoids IEEE div sequence
}
__device__ __forceinline__ int swz(int p, int cc) { return cc ^ ((p ^ (p >> 3)) & 7); }

// ws layout (floats):
//   stats: wsf[16*s+0]=sum_x +1=sumsq_x +2=sum_h +3=sumsq_h  (64B line per sample, memset-zeroed)
//   consts: u1=wsf[256..319]  v1=wsf[320..383]  u2=wsf[384..399]  v2=wsf[400..415]
// bytes: a1 bf16[64][64] @2048, a2 bf16[16][64] @10240.  total need = 16384 B.

// ---- k1: x stats (streaming, full occupancy); block (0,0) preps weights ----
__global__ __launch_bounds__(256, 8) void k1(
    const float* __restrict__ x,
    const float* __restrict__ w1, const float* __restrict__ b1,
    const float* __restrict__ s1, const float* __restrict__ gb1,
    const float* __restrict__ w2, const float* __restrict__ b2,
    const float* __restrict__ s2, const float* __restrict__ gb2,
    float* __restrict__ wsf,
    unsigned short* __restrict__ a1, unsigned short* __restrict__ a2) {
  __shared__ float red[8];
  const int tid = threadIdx.x;
  const int l = tid & 63, w = tid >> 6;
  const int b = blockIdx.y;

  if (blockIdx.x == 0 && b == 0) {
    {
      int o = tid >> 2, q = tid & 3;
      float u = 0.f, v = 0.f;
      unsigned short loc[16];
#pragma unroll
      for (int i = 0; i < 16; ++i) {
        int c = q * 16 + i;
        float wv = w1[o * 64 + c];
        float wsc = wv * s1[c];
        loc[i] = f2bf(wsc);
        u += wsc;
        v += wv * gb1[c];
      }
      *(short8*)(a1 + o * 64 + q * 16) = *(short8*)loc;
      *(short8*)(a1 + o * 64 + q * 16 + 8) = *(short8*)(loc + 8);
      u += __shfl_xor(u, 1, 64); u += __shfl_xor(u, 2, 64);
      v += __shfl_xor(v, 1, 64); v += __shfl_xor(v, 2, 64);
      if (q == 0) { wsf[256 + o] = u; wsf[320 + o] = b1[o] + v; }
    }
    if (tid < 64) {
      int o = tid >> 2, q = tid & 3;
      float u = 0.f, v = 0.f;
      unsigned short loc[16];
#pragma unroll
      for (int i = 0; i < 16; ++i) {
        int c = q * 16 + i;
        float wv = (o < 6) ? w2[o * 64 + c] : 0.f;
        float wsc = wv * s2[c];
        loc[i] = f2bf(wsc);
        u += wsc;
        v += wv * gb2[c];
      }
      *(short8*)(a2 + o * 64 + q * 16) = *(short8*)loc;
      *(short8*)(a2 + o * 64 + q * 16 + 8) = *(short8*)(loc + 8);
      u += __shfl_xor(u, 1, 64); u += __shfl_xor(u, 2, 64);
      v += __shfl_xor(v, 1, 64); v += __shfl_xor(v, 2, 64);
      if (q == 0) { wsf[384 + o] = u; wsf[400 + o] = ((o < 6) ? b2[o] : 0.f) + v; }
    }
  }

  const f32x4* xb = (const f32x4*)(x + (size_t)b * CH * HW);
  const f32x4* p = xb + (size_t)blockIdx.x * 8192 + tid;
  float s = 0.f, q = 0.f;
#pragma unroll
  for (int it = 0; it < 32; ++it) {
    f32x4 v = p[it * 256];
#pragma unroll
    for (int i = 0; i < 4; ++i) { float f = v[i]; s += f; q += f * f; }
  }
#pragma unroll
  for (int off = 32; off > 0; off >>= 1) {
    s += __shfl_down(s, off, 64);
    q += __shfl_down(q, off, 64);
  }
  if (l == 0) { red[w] = s; red[4 + w] = q; }
  __syncthreads();
  if (tid == 0) {
    atomicAdd(wsf + 16 * b + 0, red[0] + red[1] + red[2] + red[3]);
    atomicAdd(wsf + 16 * b + 1, red[4] + red[5] + red[6] + red[7]);
  }
}

// ---- k2: x (reverse, L3-hot) -> conv1 MFMA -> silu+h-stats -> conv2 -> raw y ----
__global__ __launch_bounds__(256, 4) void k2(const float* __restrict__ x,
                                             const unsigned short* __restrict__ a1,
                                             const unsigned short* __restrict__ a2,
                                             const float* __restrict__ wsf,
                                             float* __restrict__ wstat,
                                             float* __restrict__ out) {
  __shared__ __align__(16) unsigned char tile[128 * 128];
  __shared__ float red[8];
  const int tid = threadIdx.x;
  const int l = tid & 63, w = tid >> 6;
  const int s = 15 - blockIdx.y;                 // reverse sample order
  const int ptile = (511 - blockIdx.x) * 128;    // reverse tile order
  const float* xb = x + (size_t)s * CH * HW;

  const float m1 = wsf[16 * s + 0] / NPIXF;
  const float rs1 = rsqrtf(wsf[16 * s + 1] / NPIXF - m1 * m1 + 1e-6f);

  float c1r[4][4];
#pragma unroll
  for (int mf = 0; mf < 4; ++mf) {
    const int o0 = mf * 16 + (l >> 4) * 4;
    f32x4 u = *(const f32x4*)(wsf + 256 + o0);
    f32x4 vv = *(const f32x4*)(wsf + 320 + o0);
#pragma unroll
    for (int r = 0; r < 4; ++r) c1r[mf][r] = vv[r] - rs1 * m1 * u[r];
  }

  bf16x8 af[4][2];
#pragma unroll
  for (int mf = 0; mf < 4; ++mf)
#pragma unroll
    for (int ks = 0; ks < 2; ++ks)
      af[mf][ks] = *(const bf16x8*)((const unsigned char*)a1 +
                     (mf * 16 + (l & 15)) * 128 + ks * 64 + (l >> 4) * 16);
  bf16x8 a2f[2];
#pragma unroll
  for (int ks = 0; ks < 2; ++ks)
    a2f[ks] = *(const bf16x8*)((const unsigned char*)a2 +
                 (l & 15) * 128 + ks * 64 + (l >> 4) * 16);

  const int c0 = (tid >> 5) * 8;
  const int p4 = (tid & 31) * 4;
  f32x4 v[8];
  const float* base = xb + (size_t)c0 * HW + ptile + p4;
#pragma unroll
  for (int i = 0; i < 8; ++i) v[i] = *(const f32x4*)(base + (size_t)i * HW);
#pragma unroll
  for (int dp = 0; dp < 4; ++dp) {
    int p = p4 + dp;
    short8 w8;
#pragma unroll
    for (int i = 0; i < 8; ++i) w8[i] = cvt1(v[i][dp]);
    *(short8*)(tile + p * 128 + swz(p, c0 >> 3) * 16) = w8;
  }
  __syncthreads();  // only barrier: cross-wave transpose complete

  bf16x8 bfr[2][2];
#pragma unroll
  for (int nf = 0; nf < 2; ++nf) {
    const int pl = w * 32 + nf * 16 + (l & 15);
#pragma unroll
    for (int ks = 0; ks < 2; ++ks) {
      int cc = ks * 4 + (l >> 4);
      bfr[nf][ks] = *(const bf16x8*)(tile + pl * 128 + swz(pl, cc) * 16);
    }
  }

  // phase A: t = A1*x, h = silu(rs1*t + c1) via fast rcp, h-stats, h -> tile
  float hs = 0.f, hq = 0.f;
#pragma unroll
  for (int nf = 0; nf < 2; ++nf) {
    const int pl = w * 32 + nf * 16 + (l & 15);
#pragma unroll
    for (int mf = 0; mf < 4; ++mf) {
      f32x4 acc = {0.f, 0.f, 0.f, 0.f};
      acc = __builtin_amdgcn_mfma_f32_16x16x32_bf16(af[mf][0], bfr[nf][0], acc, 0, 0, 0);
      acc = __builtin_amdgcn_mfma_f32_16x16x32_bf16(af[mf][1], bfr[nf][1], acc, 0, 0, 0);
      const int o0 = mf * 16 + (l >> 4) * 4;
      short4v hv;
#pragma unroll
      for (int r = 0; r < 4; ++r) {
        float z = rs1 * acc[r] + c1r[mf][r];
        float hh = z * fastrcp(1.f + __expf(-z));   // was IEEE div (~10 ops)
        hs += hh; hq += hh * hh;
        hv[r] = cvt1(hh);
      }
      *(short4v*)(tile + pl * 128 + swz(pl, o0 >> 3) * 16 + (o0 & 7) * 2) = hv;
    }
  }
  // no barrier: phase B reads only rows this wave wrote

  float* ob = out + (size_t)s * 6 * HW;
#pragma unroll
  for (int nf = 0; nf < 2; ++nf) {
    const int pl = w * 32 + nf * 16 + (l & 15);
    const int p = ptile + pl;
    bf16x8 hfr[2];
#pragma unroll
    for (int ks = 0; ks < 2; ++ks) {
      int cc = ks * 4 + (l >> 4);
      hfr[ks] = *(const bf16x8*)(tile + pl * 128 + swz(pl, cc) * 16);
    }
    f32x4 acc = {0.f, 0.f, 0.f, 0.f};
    acc = __builtin_amdgcn_mfma_f32_16x16x32_bf16(a2f[0], hfr[0], acc, 0, 0, 0);
    acc = __builtin_amdgcn_mfma_f32_16x16x32_bf16(a2f[1], hfr[1], acc, 0, 0, 0);
    const int ob0 = (l >> 4) * 4;
#pragma unroll
    for (int r = 0; r < 4; ++r) {
      int o = ob0 + r;
      if (o < 6) ob[(size_t)o * HW + p] = acc[r];
    }
  }

#pragma unroll
  for (int off = 32; off > 0; off >>= 1) {
    hs += __shfl_down(hs, off, 64);
    hq += __shfl_down(hq, off, 64);
  }
  if (l == 0) { red[w] = hs; red[4 + w] = hq; }
  __syncthreads();
  if (tid == 0) {
    atomicAdd(wstat + 16 * s + 2, red[0] + red[1] + red[2] + red[3]);
    atomicAdd(wstat + 16 * s + 3, red[4] + red[5] + red[6] + red[7]);
  }
}

// ---- k3: out = rs2*out + c2[o]  (in-place, elementwise; reverse order) ----
__global__ __launch_bounds__(256) void k3(float* __restrict__ out,
                                          const float* __restrict__ wsf) {
  const int s = 15 - blockIdx.y;
  const float m2 = wsf[16 * s + 2] / NPIXF;
  const float rs2 = rsqrtf(wsf[16 * s + 3] / NPIXF - m2 * m2 + 1e-6f);
  float* ob = out + (size_t)s * 6 * HW;
#pragma unroll
  for (int it = 0; it < 4; ++it) {
    int f4 = blockIdx.x * 256 + threadIdx.x + it * 24576;  // < 98304
    int o = f4 >> 14;
    float c2 = wsf[400 + o] - rs2 * m2 * wsf[384 + o];
    f32x4* p = (f32x4*)ob + f4;
    f32x4 v = *p;
#pragma unroll
    for (int i = 0; i < 4; ++i) v[i] = rs2 * v[i] + c2;
    *p = v;
  }
}

extern "C" void kernel_launch(void* const* d_in, const int* in_sizes, int n_in,
                              void* d_out, int out_size, void* d_ws, size_t ws_size,
                              hipStream_t stream) {
  const float* x  = (const float*)d_in[0];
  const float* s1 = (const float*)d_in[1];
  const float* g1 = (const float*)d_in[2];
  const float* w1 = (const float*)d_in[3];
  const float* b1 = (const float*)d_in[4];
  const float* s2 = (const float*)d_in[5];
  const float* g2 = (const float*)d_in[6];
  const float* w2 = (const float*)d_in[7];
  const float* b2 = (const float*)d_in[8];
  float* out = (float*)d_out;
  float* wsf = (float*)d_ws;
  unsigned short* a1 = (unsigned short*)((char*)d_ws + 2048);
  unsigned short* a2 = (unsigned short*)((char*)d_ws + 10240);

  if (ws_size < 16384) return;

  hipMemsetAsync(d_ws, 0, 1024, stream);  // zero per-sample stat lines
  k1<<<dim3(128, 16), 256, 0, stream>>>(x, w1, b1, s1, g1, w2, b2, s2, g2, wsf, a1, a2);
  k2<<<dim3(512, 16), 256, 0, stream>>>(x, a1, a2, wsf, wsf, out);
  k3<<<dim3(96, 16), 256, 0, stream>>>(out, wsf);
}